// Round 5
// baseline (81.063 us; speedup 1.0000x reference)
//
#include <hip/hip_runtime.h>
#include <cstdint>

// Problem constants (from reference)
#define B 64
#define P 5000
#define G 300
#define C 20
#define SCALE_F 512.0f
#define IOU_TH 0.5f
#define NTA 1024                              // 16 waves; one block per image
#define NWAVE (NTA / 64)                      // 16
#define SPT ((P + NTA - 1) / NTA)             // 5 pred slots per thread
#define NCHUNK ((G + 63) / 64)                // 5 target wave-chunks
#define SENT 0x7FFFFFFF

// Match numpy float32 semantics exactly: no FMA contraction (hipcc defaults
// to contract=fast). Division stays IEEE (no fast-math).
#pragma clang fp contract(off)

// ---------------------------------------------------------------------------
// Round-5 structural collapse: ONE kernel, ONE block per image (64 x 1024).
// Rationale from rounds 1-4: the IoU loop is ~2us of chip VALU; all per-pred
// data-path variants were within +-4us; round-2 showed duplicated per-block
// staging costs ~4.5us/block on the critical path. So: stage each image
// EXACTLY ONCE, resolve claims entirely in LDS (firstp), write winners
// in-kernel, and drop the resolve kernel + its launch gap + all blockfp
// workspace traffic. Only 64 CUs are used, but the per-block work (~10us)
// replaces a 2-dispatch pipeline that measured ~25us end-to-end.
// Data path = round-3 proven: ballot-ranked STABLE target class-sort
// (chunk-major + lane order == original index order -> preserves the
// jnp.argmax first-occurrence tie-break), atomic-cursor unstable pred sort
// (order within bucket irrelevant: claims use atomicMin on the true pred
// index), scattered global pred reads in the match loop (round-3 measured
// best), coalesced dense stats store in the p-ordered phase.
// Winner write: corr=0 stored in P1, overwritten to 1.0 in P6 by a different
// thread of the SAME block; the intervening __syncthreads orders the two
// same-address global stores (block-scope ordering; host reads after kernel
// end). Semantics: reference scan == "first eligible claimant (lowest p) per
// target wins" == LDS atomicMin over the whole image.
// ---------------------------------------------------------------------------
__global__ __launch_bounds__(NTA, 4) void match_kernel(
    const float* __restrict__ preds,      // [B,P,6]
    const float* __restrict__ labels,     // [B,G,5]
    float* __restrict__ out_stats,        // [B,P,3]
    float* __restrict__ out_tcls)         // [B,G]
{
    const int b = blockIdx.x;
    const int tid = threadIdx.x;
    const int lane = tid & 63;
    const int w = tid >> 6;

    __shared__ float4 sb[G];              // class-sorted scaled target boxes
    __shared__ float  sa[G];              // areas
    __shared__ short  ssi[G];             // sorted pos -> original target idx
    __shared__ int    chist[NCHUNK][C];   // per-wave-chunk target class counts
    __shared__ int    so[C + 1];          // target bucket offsets
    __shared__ int    pcnt[C];            // pred histogram -> scatter cursor
    __shared__ int    firstp[G];          // image-global lowest claimant
    __shared__ unsigned short psorted[P]; // sorted slot -> pred idx (10 KB)

    const float* lab = labels + (size_t)b * G * 5;
    const float* prd = preds + (size_t)b * P * 6;

    // ---- P1: inits + target load/ballot-hist + pred class/stats store ----
    if (tid < C) pcnt[tid] = 0;
    if (tid < G) firstp[tid] = SENT;

    float tx1 = 0, ty1 = 0, tx2 = 0, ty2 = 0;
    int tc = -1;
    unsigned long long tmask = 0;
    if (tid < NCHUNK * 64) {              // waves 0..4 fully active for ballot
        if (tid < G) {
            tx1 = lab[tid * 5 + 0];
            ty1 = lab[tid * 5 + 1];
            tx2 = lab[tid * 5 + 2];
            ty2 = lab[tid * 5 + 3];
            float cf = lab[tid * 5 + 4];
            tc = (int)cf;
            out_tcls[(size_t)b * G + tid] = cf;
        }
        #pragma unroll
        for (int cc = 0; cc < C; ++cc) {
            unsigned long long m = __ballot(tc == cc);
            if (tc == cc) tmask = m;                       // keep for scatter
            if (lane == cc) chist[w][cc] = __popcll(m);    // race-free write
        }
    }

    int myc[SPT];                          // pred class cached across phases
    #pragma unroll
    for (int k = 0; k < SPT; ++k) {
        myc[k] = -1;
        int p = k * NTA + tid;
        if (p < P) {
            // (score, cls) as one 8B load; p-order => coalesced
            float2 sc = *reinterpret_cast<const float2*>(prd + (size_t)p * 6 + 4);
            myc[k] = (int)sc.y;
            size_t ip3 = ((size_t)b * P + p) * 3;
            out_stats[ip3 + 0] = 0.0f;     // winners flipped to 1.0 in P6
            out_stats[ip3 + 1] = sc.x;
            out_stats[ip3 + 2] = sc.y;
        }
    }
    __syncthreads();                       // pcnt init visible before atomics

    // ---- P2: pred class histogram (LDS atomics, 20-way spread) ----
    #pragma unroll
    for (int k = 0; k < SPT; ++k)
        if (myc[k] >= 0) atomicAdd(&pcnt[myc[k]], 1);
    __syncthreads();

    // ---- P3: scans (wave 0: targets+bases; tid 64: pred exclusive) ----
    if (tid < 64) {
        int run = 0;
        if (lane < C) {
            #pragma unroll
            for (int u = 0; u < NCHUNK; ++u) {
                int t = chist[u][lane]; chist[u][lane] = run; run += t;
            }
        }
        int v = (lane < C) ? run : 0;      // inclusive scan over class lanes
        #pragma unroll
        for (int d = 1; d < 32; d <<= 1) {
            int o = __shfl_up(v, d);
            if (lane >= d) v += o;
        }
        if (lane < C) so[lane + 1] = v;
        if (lane == 0) so[0] = 0;
    }
    if (tid == 64) {                       // wave 1: pred-class excl scan
        int a = 0;
        for (int c = 0; c < C; ++c) { int v = pcnt[c]; pcnt[c] = a; a += v; }
    }
    __syncthreads();

    // ---- P4: scatters ----
    if (tid < G) {                         // stable: chunk-major + lane order
        int rank = chist[w][tc] + __popcll(tmask & ((1ull << lane) - 1));
        int pos = so[tc] + rank;
        float x1 = tx1 * SCALE_F;          // *512 exact (pow2)
        float y1 = ty1 * SCALE_F;
        float x2 = tx2 * SCALE_F;
        float y2 = ty2 * SCALE_F;
        sb[pos] = make_float4(x1, y1, x2, y2);
        sa[pos] = (x2 - x1) * (y2 - y1);
        ssi[pos] = (short)tid;
    }
    #pragma unroll
    for (int k = 0; k < SPT; ++k) {
        int p = k * NTA + tid;
        if (p < P) {
            int pos = atomicAdd(&pcnt[myc[k]], 1);   // cursor from class base
            psorted[pos] = (unsigned short)p;
        }
    }
    __syncthreads();

    // ---- P5: match (slot-ordered: lanes mostly same class) ----
    #pragma unroll
    for (int k = 0; k < SPT; ++k) {
        int slot = k * NTA + tid;
        if (slot >= P) continue;
        int p = psorted[slot];
        const float* pr = prd + (size_t)p * 6;
        float2 q0 = *reinterpret_cast<const float2*>(pr);       // x1,y1
        float2 q1 = *reinterpret_cast<const float2*>(pr + 2);   // x2,y2
        float2 q2 = *reinterpret_cast<const float2*>(pr + 4);   // score,cls
        float px1 = q0.x * SCALE_F;
        float py1 = q0.y * SCALE_F;
        float px2 = q1.x * SCALE_F;
        float py2 = q1.y * SCALE_F;
        float score = q2.x;
        int c = (int)q2.y;
        float parea = (px2 - px1) * (py2 - py1);

        int lo = so[c], hi = so[c + 1];
        float best = -1.0f;
        int bi = -1;
        // bucket preserves original order; strict > keeps FIRST max occurrence
        for (int j = lo; j < hi; ++j) {
            float4 tb = sb[j];                 // few distinct j per wave
            float lx = fmaxf(px1, tb.x);
            float ly = fmaxf(py1, tb.y);
            float rx = fminf(px2, tb.z);
            float ry = fminf(py2, tb.w);
            float wd = fmaxf(rx - lx, 0.0f);
            float ht = fmaxf(ry - ly, 0.0f);
            float inter = wd * ht;
            float uni = (parea + sa[j]) - inter;   // reference assoc order
            float iou = inter / uni;               // IEEE div
            if (iou > best) { best = iou; bi = ssi[j]; }
        }

        bool eligible = (score > 0.0f) && (hi > lo) && (best > IOU_TH);
        if (eligible) atomicMin(&firstp[bi], p);
    }
    __syncthreads();

    // ---- P6: winners (sparse; a pred wins at most one target) ----
    if (tid < G) {
        int m = firstp[tid];
        if (m != SENT)
            out_stats[((size_t)b * P + m) * 3] = 1.0f;
    }
}

extern "C" void kernel_launch(void* const* d_in, const int* in_sizes, int n_in,
                              void* d_out, int out_size, void* d_ws, size_t ws_size,
                              hipStream_t stream) {
    const float* output = (const float*)d_in[0];   // [B,P,6]
    const float* labels = (const float*)d_in[1];   // [B,G,5]

    float* out_stats = (float*)d_out;                       // [B,P,3]
    float* out_tcls  = (float*)d_out + (size_t)B * P * 3;   // [B,G]

    // single dispatch; workspace unused (no cross-block state at all)
    match_kernel<<<dim3(B), NTA, 0, stream>>>(output, labels,
                                              out_stats, out_tcls);
}